// Round 8
// baseline (184.963 us; speedup 1.0000x reference)
//
#include <hip/hip_runtime.h>
#include <hip/hip_bf16.h>
#include <hip/hip_fp16.h>

#define NB 8
#define NN 256
#define DD 64

// workspace layout (float offsets)
#define OFF_WCF   0        // 2048 f = 4096 f16 : Wc B-frags [ks][nt][lane][8]
#define OFF_W1F   2048     // 2048 f = 4096 f16 : 0.25*Ws1 B-frags, same order
#define OFF_CSF   4096     // 1536 f = 3072 f16 : h-coefs per lane [lane][coef][kslot16], stride 48
#define OFF_CC    5632     // 64   : cc[d] = 0.5*(bv2@Ws1)[d] + bs1[d]
#define OFF_CNT   5696     // 8 unsigned : per-batch completion counters
#define OFF_MI    5704     // 2048 : per-row local max
#define OFF_RSI   7752     // 2048 : per-row rowsum (local frame)
#define OFF_SHR   9800     // 131072 : per-row Sh[64] (local frame)

typedef __attribute__((ext_vector_type(4))) float f32x4;
typedef _Float16 f16x8 __attribute__((ext_vector_type(8)));

static __device__ __forceinline__ f16x8 cvt8(const float* __restrict__ p) {
    float4 a = *(const float4*)p;
    float4 c = *(const float4*)(p + 4);
    f16x8 r;
    r[0] = (_Float16)a.x; r[1] = (_Float16)a.y; r[2] = (_Float16)a.z; r[3] = (_Float16)a.w;
    r[4] = (_Float16)c.x; r[5] = (_Float16)c.y; r[6] = (_Float16)c.z; r[7] = (_Float16)c.w;
    return r;
}

// ---------------------------------------------------------------- setup ----
// 11336 items: WCF 4096 | W1F 4096 | CSF 3072 | CC 64 | CNT 8
__global__ __launch_bounds__(256) void k_setup(
    const float* __restrict__ Wv1, const float* __restrict__ bv1,
    const float* __restrict__ Wv2, const float* __restrict__ bv2,
    const float* __restrict__ Ws1, const float* __restrict__ bs1,
    float* __restrict__ ws)
{
    int idx = blockIdx.x * 256 + threadIdx.x;
    if (idx < 4096) {
        // Wc = 0.5*Wv2@Ws1 -> f16 B-fragment order
        int e = idx;
        int j = e & 7, ln = (e >> 3) & 63, nt = (e >> 9) & 3, ks = e >> 11;
        int k = ks * 32 + (ln >> 4) * 8 + j;
        int d = nt * 16 + (ln & 15);
        float s = 0.f;
#pragma unroll 8
        for (int m = 0; m < 64; m++) s = fmaf(Wv2[k * 64 + m], Ws1[m * 64 + d], s);
        ((_Float16*)(ws + OFF_WCF))[e] = (_Float16)(0.5f * s);
    } else if (idx < 8192) {
        // 0.25*Ws1 -> f16 B-fragment order
        int e = idx - 4096;
        int j = e & 7, ln = (e >> 3) & 63, nt = (e >> 9) & 3, ks = e >> 11;
        int k = ks * 32 + (ln >> 4) * 8 + j;
        int d = nt * 16 + (ln & 15);
        ((_Float16*)(ws + OFF_W1F))[e] = (_Float16)(0.25f * Ws1[k * 64 + d]);
    } else if (idx < 11264) {
        // h-coefs: stride-48 per lane: [lane][coef(3)][kslot(16)]
        int e = idx - 8192;            // 0..3071
        int ln = e / 48;
        int rem = e - ln * 48;
        int coef = rem >> 4, kslot = rem & 15;
        int ks = kslot >> 3, j = kslot & 7;
        int k = ks * 32 + (ln >> 4) * 8 + j;
        float v = (coef == 0) ? Wv1[k] : (coef == 1) ? Wv1[64 + k] : bv1[k];
        ((_Float16*)(ws + OFF_CSF))[ln * 48 + coef * 16 + kslot] = (_Float16)v;
    } else if (idx < 11328) {
        int d = idx - 11264;
        float s = 0.f;
#pragma unroll 8
        for (int k = 0; k < 64; k++) s = fmaf(bv2[k], Ws1[k * 64 + d], s);
        ws[OFF_CC + d] = 0.5f * s + bs1[d];
    } else if (idx < 11336) {
        ((unsigned*)(ws + OFF_CNT))[idx - 11328] = 0u;
    }
}

// ----------------------------------------------------------------- main ----
// 1024 blocks = 8 batches * 128 i-pairs; 256 threads (4 waves).
// Phase 1: K=128 MFMA GEMM -> scores in LDS. Phase 2: row-local softmax+Sh.
// Phase 3 (last block per batch): cross-row combine -> output.
__global__ __launch_bounds__(256, 4) void k_main(
    const float* __restrict__ pos, const float* __restrict__ values,
    const float* __restrict__ Wv1, const float* __restrict__ bv1,
    const float* __restrict__ Wv2, const float* __restrict__ bv2,
    const float* __restrict__ Ws2, float* __restrict__ ws,
    float* __restrict__ out)
{
    __shared__ float2   ldsDB[2 * 256];   // (dot,biv)
    __shared__ float    ldsS[2][256];     // scores, then weights
    __shared__ float    ldsCCU[2 * 64];   // cc + u_i
    __shared__ float    ldsWs2[64];
    __shared__ float    ldsPos[6];
    __shared__ float    ldsRed[4];
    __shared__ float    ldsP[4][64];
    __shared__ _Float16 ldsW1[4096];      // 0.25*Ws1 B-frags
    // final-phase scratch (only last block per batch uses)
    __shared__ float    fscl[256], fzl[256], fred[4], fpS[4][64], fpA[4][64], fshv[64], fa2v[64];
    __shared__ unsigned s_last;

    int b  = blockIdx.x >> 7;
    int i0 = (blockIdx.x & 127) * 2;
    int t  = threadIdx.x;
    int lane = t & 63, wv = t >> 6;
    int q = lane >> 4, col = lane & 15;

    // ---- stage constants ----
    {   // ldsW1: 2048 floats as float4
        const float4* src = (const float4*)(ws + OFF_W1F);
        float4* dst = (float4*)ldsW1;
        dst[t] = src[t];
        dst[256 + t] = src[256 + t];
    }
    if (t < 6)  ldsPos[t] = pos[(b * 256 + i0) * 3 + t];
    if (t < 64) ldsWs2[t] = Ws2[t];
    if (t < 128) ldsCCU[t] = ws[OFF_CC + (t & 63)];

    // per-lane h-coefs (f16 packed): 16 kslots x {A,B,C}
    f16x8 cfA[2], cfB[2], cfC[2];
    {
        const f16x8* cs = (const f16x8*)((const _Float16*)(ws + OFF_CSF) + lane * 48);
        cfA[0] = cs[0]; cfA[1] = cs[1];
        cfB[0] = cs[2]; cfB[1] = cs[3];
        cfC[0] = cs[4]; cfC[1] = cs[5];
    }
    // Wc B-frags in registers
    f16x8 wcf[2][4];
    {
        const f16x8* p = (const f16x8*)(ws + OFF_WCF);
#pragma unroll
        for (int ks = 0; ks < 2; ks++)
#pragma unroll
            for (int nt = 0; nt < 4; nt++)
                wcf[ks][nt] = p[(ks * 4 + nt) * 64 + lane];
    }
    __syncthreads();

    {   // dot/biv for both rows vs all j
        float px = pos[(b * 256 + t) * 3 + 0];
        float py = pos[(b * 256 + t) * 3 + 1];
        float pz = pos[(b * 256 + t) * 3 + 2];
#pragma unroll
        for (int ii = 0; ii < 2; ii++) {
            float ax = ldsPos[ii * 3 + 0], ay = ldsPos[ii * 3 + 1], az = ldsPos[ii * 3 + 2];
            float dot = ax * px + ay * py + az * pz;
            float cx = ay * pz - az * py;
            float cy = az * px - ax * pz;
            float cz = ax * py - ay * px;
            float biv = sqrtf(cx * cx + cy * cy + cz * cz + 1e-20f);
            ldsDB[ii * 256 + t] = make_float2(dot, biv);
        }
    }

    // ---- u_i via MFMA (wave 0 only): A rows 0..1 = v_{i0}, v_{i0+1} ----
    if (wv == 0) {
        const f16x8* w1 = (const f16x8*)ldsW1;
        f16x8 afu[2];
#pragma unroll
        for (int ks = 0; ks < 2; ks++) {
            if (col < 2)
                afu[ks] = cvt8(values + (b * 256 + i0 + col) * 64 + ks * 32 + q * 8);
            else
                afu[ks] = (f16x8)(_Float16)0.f;
        }
        f32x4 ua[4];
#pragma unroll
        for (int nt = 0; nt < 4; nt++) {
            ua[nt] = (f32x4){0.f, 0.f, 0.f, 0.f};
            ua[nt] = __builtin_amdgcn_mfma_f32_16x16x32_f16(afu[0], w1[(0 * 4 + nt) * 64 + lane], ua[nt], 0, 0, 0);
            ua[nt] = __builtin_amdgcn_mfma_f32_16x16x32_f16(afu[1], w1[(1 * 4 + nt) * 64 + lane], ua[nt], 0, 0, 0);
        }
        if (q == 0) {   // D rows 0..1 live in quad 0, regs r=0,1; single wave -> no race
#pragma unroll
            for (int nt = 0; nt < 4; nt++) {
#pragma unroll
                for (int r = 0; r < 2; r++)
                    ldsCCU[r * 64 + nt * 16 + col] += ua[nt][r];
            }
        }
    }
    __syncthreads();

    // ---- phase 1: K=128 MFMA GEMM S = [h|v] @ [Wc; 0.25 Ws1] ----
    const f16x8* w1 = (const f16x8*)ldsW1;

#pragma unroll
    for (int jt4 = 0; jt4 < 4; jt4++) {
        int jt = wv * 4 + jt4;
        // v A-frags for this j-tile (shared across ii), on-the-fly f32->f16
        f16x8 av[2];
#pragma unroll
        for (int ks = 0; ks < 2; ks++)
            av[ks] = cvt8(values + (b * 256 + jt * 16 + col) * 64 + ks * 32 + q * 8);

#pragma unroll
        for (int ii = 0; ii < 2; ii++) {
            float2 db = ldsDB[ii * 256 + jt * 16 + col];
            _Float16 dh = (_Float16)db.x, bh = (_Float16)db.y;
            f16x8 d8, b8;
#pragma unroll
            for (int p = 0; p < 8; p++) { d8[p] = dh; b8[p] = bh; }
            f16x8 af[2];
#pragma unroll
            for (int ks = 0; ks < 2; ks++) {
                f16x8 h = d8 * cfA[ks] + b8 * cfB[ks] + cfC[ks];
                af[ks] = __builtin_elementwise_max(h, (f16x8)(_Float16)0.f);
            }
            f32x4 acc[4];
#pragma unroll
            for (int nt = 0; nt < 4; nt++) {
                acc[nt] = (f32x4){0.f, 0.f, 0.f, 0.f};
                acc[nt] = __builtin_amdgcn_mfma_f32_16x16x32_f16(av[0], w1[(0 * 4 + nt) * 64 + lane], acc[nt], 0, 0, 0);
                acc[nt] = __builtin_amdgcn_mfma_f32_16x16x32_f16(av[1], w1[(1 * 4 + nt) * 64 + lane], acc[nt], 0, 0, 0);
                acc[nt] = __builtin_amdgcn_mfma_f32_16x16x32_f16(af[0], wcf[0][nt], acc[nt], 0, 0, 0);
                acc[nt] = __builtin_amdgcn_mfma_f32_16x16x32_f16(af[1], wcf[1][nt], acc[nt], 0, 0, 0);
            }
            // epilogue: + (cc + u_i), relu, *Ws2, reduce over d
            float tr[4] = {0.f, 0.f, 0.f, 0.f};
#pragma unroll
            for (int nt = 0; nt < 4; nt++) {
                float cu = ldsCCU[ii * 64 + nt * 16 + col];
                float w2 = ldsWs2[nt * 16 + col];
#pragma unroll
                for (int r = 0; r < 4; r++) {
                    float s = acc[nt][r] + cu;
                    tr[r] = fmaf(fmaxf(s, 0.f), w2, tr[r]);
                }
            }
#pragma unroll
            for (int m = 1; m < 16; m <<= 1) {
#pragma unroll
                for (int r = 0; r < 4; r++) tr[r] += __shfl_xor(tr[r], m);
            }
            if (col == 0) {
                float4 sc4 = make_float4(tr[0], tr[1], tr[2], tr[3]);
                *(float4*)&ldsS[ii][jt * 16 + q * 4] = sc4;
            }
        }
    }
    __syncthreads();

    // ---- phase 2: row-local softmax + Sh ----
    float A = Wv1[lane], B = Wv1[64 + lane], C = bv1[lane];
#pragma unroll
    for (int ii = 0; ii < 2; ii++) {
        float sv = ldsS[ii][t];
        float wm = sv;
#pragma unroll
        for (int md = 1; md < 64; md <<= 1) wm = fmaxf(wm, __shfl_xor(wm, md));
        if (lane == 0) ldsRed[wv] = wm;
        __syncthreads();
        float m_row = fmaxf(fmaxf(ldsRed[0], ldsRed[1]), fmaxf(ldsRed[2], ldsRed[3]));
        float wgt = __expf(sv - m_row);
        float rsp = wgt;
#pragma unroll
        for (int md = 1; md < 64; md <<= 1) rsp += __shfl_xor(rsp, md);
        ldsS[ii][t] = wgt;                 // own-slot overwrite, safe
        __syncthreads();                   // ldsRed reuse + wgt visible
        if (lane == 0) ldsRed[wv] = rsp;
        __syncthreads();
        float rowsum = ldsRed[0] + ldsRed[1] + ldsRed[2] + ldsRed[3];

        float acc = 0.f;                   // lane = k; wave sums its 64 j's
#pragma unroll 8
        for (int jj = 0; jj < 64; jj++) {
            int j = wv * 64 + jj;
            float w = ldsS[ii][j];         // broadcast read
            float2 db = ldsDB[ii * 256 + j];
            float h = fmaxf(fmaf(db.x, A, fmaf(db.y, B, C)), 0.f);
            acc = fmaf(w, h, acc);
        }
        ldsP[wv][lane] = acc;
        __syncthreads();
        int row = b * 256 + i0 + ii;
        if (t < 64)
            ws[OFF_SHR + row * 64 + t] = ldsP[0][t] + ldsP[1][t] + ldsP[2][t] + ldsP[3][t];
        if (t == 0) { ws[OFF_MI + row] = m_row; ws[OFF_RSI + row] = rowsum; }
        __syncthreads();
    }

    // ---- phase 3: last block of this batch combines all 256 rows ----
    __threadfence();
    if (t == 0) {
        unsigned old = __hip_atomic_fetch_add((unsigned*)(ws + OFF_CNT) + b, 1u,
                                              __ATOMIC_ACQ_REL, __HIP_MEMORY_SCOPE_AGENT);
        s_last = (old == 127u) ? 1u : 0u;
    }
    __syncthreads();
    if (s_last) {
        __threadfence();   // acquire side: see all rows' MI/RSI/SHR
        float mi = ws[OFF_MI + b * 256 + t];
        float wm = mi;
#pragma unroll
        for (int md = 1; md < 64; md <<= 1) wm = fmaxf(wm, __shfl_xor(wm, md));
        if (lane == 0) fred[wv] = wm;
        __syncthreads();
        float M = fmaxf(fmaxf(fred[0], fred[1]), fmaxf(fred[2], fred[3]));

        float rs = ws[OFF_RSI + b * 256 + t];
        float sc = __expf(mi - M);
        float zt = sc * rs;
        fscl[t] = sc; fzl[t] = zt;
        float zp = zt;
#pragma unroll
        for (int md = 1; md < 64; md <<= 1) zp += __shfl_xor(zp, md);
        __syncthreads();
        if (lane == 0) fred[wv] = zp;
        __syncthreads();
        float Z = fred[0] + fred[1] + fred[2] + fred[3];

        float accS = 0.f, accA = 0.f;
        const float* shrB = ws + OFF_SHR + b * 256 * 64;
        const float* vB   = values + b * 256 * 64;
#pragma unroll 4
        for (int jj = 0; jj < 64; jj++) {
            int row = wv * 64 + jj;
            accS = fmaf(fscl[row], shrB[row * 64 + lane], accS);
            accA = fmaf(fzl[row],  vB[row * 64 + lane],  accA);
        }
        fpS[wv][lane] = accS; fpA[wv][lane] = accA;
        __syncthreads();
        if (t < 64) {
            fshv[t] = fpS[0][t] + fpS[1][t] + fpS[2][t] + fpS[3][t];
            fa2v[t] = fpA[0][t] + fpA[1][t] + fpA[2][t] + fpA[3][t];
        }
        __syncthreads();
        if (t < 64) {
            float t1 = 0.f;
#pragma unroll 8
            for (int k = 0; k < 64; k++) t1 = fmaf(fshv[k], Wv2[k * 64 + t], t1);
            out[b * 64 + t] = 0.5f * (t1 + fa2v[t]) / Z + 0.5f * bv2[t];
        }
    }
}

// ---------------------------------------------------------------- launch ---
extern "C" void kernel_launch(void* const* d_in, const int* in_sizes, int n_in,
                              void* d_out, int out_size, void* d_ws, size_t ws_size,
                              hipStream_t stream)
{
    const float* positions = (const float*)d_in[0];
    const float* values    = (const float*)d_in[1];
    const float* Wv1       = (const float*)d_in[2];
    const float* bv1       = (const float*)d_in[3];
    const float* Wv2       = (const float*)d_in[4];
    const float* bv2       = (const float*)d_in[5];
    const float* Ws1       = (const float*)d_in[6];
    const float* bs1       = (const float*)d_in[7];
    const float* Ws2       = (const float*)d_in[8];
    // d_in[9] = bs2: uniform shift on scores, cancels in softmax
    float* ws  = (float*)d_ws;
    float* out = (float*)d_out;

    k_setup<<<45, 256, 0, stream>>>(Wv1, bv1, Wv2, bv2, Ws1, bs1, ws);
    k_main<<<1024, 256, 0, stream>>>(positions, values, Wv1, bv1, Wv2, bv2, Ws2, ws, out);
}

// Round 9
// 104.770 us; speedup vs baseline: 1.7654x; 1.7654x over previous
//
#include <hip/hip_runtime.h>
#include <hip/hip_bf16.h>
#include <hip/hip_fp16.h>

#define NB 8
#define NN 256
#define DD 64

// workspace layout (float offsets)
#define OFF_WCF   0        // 2048 f = 4096 f16 : Wc B-frags [ks][nt][lane][8]
#define OFF_W1F   2048     // 2048 f = 4096 f16 : 0.25*Ws1 B-frags, same order
#define OFF_CSF   4096     // 1536 f = 3072 f16 : h-coefs per lane [lane][coef][kslot16], stride 48
#define OFF_CC    5632     // 64   : cc[d] = 0.5*(bv2@Ws1)[d] + bs1[d]
#define OFF_MI    5704     // 2048 : per-row local max
#define OFF_RSI   7752     // 2048 : per-row rowsum (local frame)
#define OFF_SHR   9800     // 131072 : per-row Sh[64] (local frame)

typedef __attribute__((ext_vector_type(4))) float f32x4;
typedef _Float16 f16x8 __attribute__((ext_vector_type(8)));

static __device__ __forceinline__ f16x8 cvt8(const float* __restrict__ p) {
    float4 a = *(const float4*)p;
    float4 c = *(const float4*)(p + 4);
    f16x8 r;
    r[0] = (_Float16)a.x; r[1] = (_Float16)a.y; r[2] = (_Float16)a.z; r[3] = (_Float16)a.w;
    r[4] = (_Float16)c.x; r[5] = (_Float16)c.y; r[6] = (_Float16)c.z; r[7] = (_Float16)c.w;
    return r;
}

// ---------------------------------------------------------------- setup ----
// 11328 items: WCF 4096 | W1F 4096 | CSF 3072 | CC 64
__global__ __launch_bounds__(256) void k_setup(
    const float* __restrict__ Wv1, const float* __restrict__ bv1,
    const float* __restrict__ Wv2, const float* __restrict__ bv2,
    const float* __restrict__ Ws1, const float* __restrict__ bs1,
    float* __restrict__ ws)
{
    int idx = blockIdx.x * 256 + threadIdx.x;
    if (idx < 4096) {
        // Wc = 0.5*Wv2@Ws1 -> f16 B-fragment order
        int e = idx;
        int j = e & 7, ln = (e >> 3) & 63, nt = (e >> 9) & 3, ks = e >> 11;
        int k = ks * 32 + (ln >> 4) * 8 + j;
        int d = nt * 16 + (ln & 15);
        float s = 0.f;
#pragma unroll 8
        for (int m = 0; m < 64; m++) s = fmaf(Wv2[k * 64 + m], Ws1[m * 64 + d], s);
        ((_Float16*)(ws + OFF_WCF))[e] = (_Float16)(0.5f * s);
    } else if (idx < 8192) {
        // 0.25*Ws1 -> f16 B-fragment order
        int e = idx - 4096;
        int j = e & 7, ln = (e >> 3) & 63, nt = (e >> 9) & 3, ks = e >> 11;
        int k = ks * 32 + (ln >> 4) * 8 + j;
        int d = nt * 16 + (ln & 15);
        ((_Float16*)(ws + OFF_W1F))[e] = (_Float16)(0.25f * Ws1[k * 64 + d]);
    } else if (idx < 11264) {
        // h-coefs: stride-48 per lane: [lane][coef(3)][kslot(16)]
        int e = idx - 8192;            // 0..3071
        int ln = e / 48;
        int rem = e - ln * 48;
        int coef = rem >> 4, kslot = rem & 15;
        int ks = kslot >> 3, j = kslot & 7;
        int k = ks * 32 + (ln >> 4) * 8 + j;
        float v = (coef == 0) ? Wv1[k] : (coef == 1) ? Wv1[64 + k] : bv1[k];
        ((_Float16*)(ws + OFF_CSF))[ln * 48 + coef * 16 + kslot] = (_Float16)v;
    } else if (idx < 11328) {
        int d = idx - 11264;
        float s = 0.f;
#pragma unroll 8
        for (int k = 0; k < 64; k++) s = fmaf(bv2[k], Ws1[k * 64 + d], s);
        ws[OFF_CC + d] = 0.5f * s + bs1[d];
    }
}

// ----------------------------------------------------------------- main ----
// 1024 blocks = 8 batches * 128 i-pairs; 256 threads (4 waves).
// Phase 1: K=128 MFMA GEMM -> scores in LDS. Phase 2: row-local softmax+Sh
// -> per-row record {m, rowsum, Sh[64]} in ws. (k_final combines rows.)
__global__ __launch_bounds__(256, 4) void k_main(
    const float* __restrict__ pos, const float* __restrict__ values,
    const float* __restrict__ Wv1, const float* __restrict__ bv1,
    const float* __restrict__ Ws2, float* __restrict__ ws)
{
    __shared__ float    ldsDB[256 * 4];   // per j: {dot0,biv0,dot1,biv1}
    __shared__ float    ldsS[256 * 2];    // per j: {s0,s1} scores, then weights
    __shared__ float    ldsCCU[2 * 64];   // cc + u_i per row
    __shared__ float    ldsWs2[64];
    __shared__ float    ldsPos[6];
    __shared__ float    ldsRedM[2][4];
    __shared__ float    ldsRedS[2][4];
    __shared__ float    ldsP[2][4][64];
    __shared__ _Float16 ldsW1[4096];      // 0.25*Ws1 B-frags

    int b  = blockIdx.x >> 7;
    int i0 = (blockIdx.x & 127) * 2;
    int t  = threadIdx.x;
    int lane = t & 63, wv = t >> 6;
    int q = lane >> 4, col = lane & 15;

    // ---- stage constants ----
    {
        const float4* src = (const float4*)(ws + OFF_W1F);
        float4* dst = (float4*)ldsW1;
        dst[t] = src[t];
        dst[256 + t] = src[256 + t];
    }
    if (t < 6)  ldsPos[t] = pos[(b * 256 + i0) * 3 + t];
    if (t < 64) ldsWs2[t] = Ws2[t];
    if (t < 128) ldsCCU[t] = ws[OFF_CC + (t & 63)];

    // per-lane h-coefs (f16 packed)
    f16x8 cfA[2], cfB[2], cfC[2];
    {
        const f16x8* cs = (const f16x8*)((const _Float16*)(ws + OFF_CSF) + lane * 48);
        cfA[0] = cs[0]; cfA[1] = cs[1];
        cfB[0] = cs[2]; cfB[1] = cs[3];
        cfC[0] = cs[4]; cfC[1] = cs[5];
    }
    // Wc B-frags in registers
    f16x8 wcf[2][4];
    {
        const f16x8* p = (const f16x8*)(ws + OFF_WCF);
#pragma unroll
        for (int ks = 0; ks < 2; ks++)
#pragma unroll
            for (int nt = 0; nt < 4; nt++)
                wcf[ks][nt] = p[(ks * 4 + nt) * 64 + lane];
    }
    __syncthreads();

    {   // dot/biv for both rows vs all j, interleaved float4 per j
        float px = pos[(b * 256 + t) * 3 + 0];
        float py = pos[(b * 256 + t) * 3 + 1];
        float pz = pos[(b * 256 + t) * 3 + 2];
        float4 r;
        {
            float ax = ldsPos[0], ay = ldsPos[1], az = ldsPos[2];
            r.x = ax * px + ay * py + az * pz;
            float cx = ay * pz - az * py, cy = az * px - ax * pz, cz = ax * py - ay * px;
            r.y = sqrtf(cx * cx + cy * cy + cz * cz + 1e-20f);
        }
        {
            float ax = ldsPos[3], ay = ldsPos[4], az = ldsPos[5];
            r.z = ax * px + ay * py + az * pz;
            float cx = ay * pz - az * py, cy = az * px - ax * pz, cz = ax * py - ay * px;
            r.w = sqrtf(cx * cx + cy * cy + cz * cz + 1e-20f);
        }
        ((float4*)ldsDB)[t] = r;
    }

    // ---- u_i via MFMA (wave 0 only): A rows 0..1 = v_{i0}, v_{i0+1} ----
    if (wv == 0) {
        const f16x8* w1 = (const f16x8*)ldsW1;
        f16x8 afu[2];
#pragma unroll
        for (int ks = 0; ks < 2; ks++) {
            if (col < 2)
                afu[ks] = cvt8(values + (b * 256 + i0 + col) * 64 + ks * 32 + q * 8);
            else
                afu[ks] = (f16x8)(_Float16)0.f;
        }
        f32x4 ua[4];
#pragma unroll
        for (int nt = 0; nt < 4; nt++) {
            ua[nt] = (f32x4){0.f, 0.f, 0.f, 0.f};
            ua[nt] = __builtin_amdgcn_mfma_f32_16x16x32_f16(afu[0], w1[(0 * 4 + nt) * 64 + lane], ua[nt], 0, 0, 0);
            ua[nt] = __builtin_amdgcn_mfma_f32_16x16x32_f16(afu[1], w1[(1 * 4 + nt) * 64 + lane], ua[nt], 0, 0, 0);
        }
        if (q == 0) {
#pragma unroll
            for (int nt = 0; nt < 4; nt++)
#pragma unroll
                for (int r = 0; r < 2; r++)
                    ldsCCU[r * 64 + nt * 16 + col] += ua[nt][r];
        }
    }
    __syncthreads();

    // preload epilogue constants into regs (replaces per-iter LDS broadcasts)
    float cu[2][4], w2r[4];
#pragma unroll
    for (int nt = 0; nt < 4; nt++) {
        cu[0][nt] = ldsCCU[nt * 16 + col];
        cu[1][nt] = ldsCCU[64 + nt * 16 + col];
        w2r[nt]   = ldsWs2[nt * 16 + col];
    }

    // ---- phase 1: S = [h|v] @ [Wc; 0.25 Ws1], u_j-part computed once ----
    const f16x8* w1 = (const f16x8*)ldsW1;

#pragma unroll
    for (int jt4 = 0; jt4 < 4; jt4++) {
        int jt = wv * 4 + jt4;
        // v A-frags, on-the-fly f32->f16
        f16x8 av[2];
#pragma unroll
        for (int ks = 0; ks < 2; ks++)
            av[ks] = cvt8(values + (b * 256 + jt * 16 + col) * 64 + ks * 32 + q * 8);

        // u_j part: shared by both rows
        f32x4 uacc[4];
#pragma unroll
        for (int nt = 0; nt < 4; nt++) {
            uacc[nt] = (f32x4){0.f, 0.f, 0.f, 0.f};
            uacc[nt] = __builtin_amdgcn_mfma_f32_16x16x32_f16(av[0], w1[(0 * 4 + nt) * 64 + lane], uacc[nt], 0, 0, 0);
            uacc[nt] = __builtin_amdgcn_mfma_f32_16x16x32_f16(av[1], w1[(1 * 4 + nt) * 64 + lane], uacc[nt], 0, 0, 0);
        }

        float4 db4 = ((const float4*)ldsDB)[jt * 16 + col];
#pragma unroll
        for (int ii = 0; ii < 2; ii++) {
            _Float16 dh = (_Float16)(ii ? db4.z : db4.x);
            _Float16 bh = (_Float16)(ii ? db4.w : db4.y);
            f16x8 d8, b8;
#pragma unroll
            for (int p = 0; p < 8; p++) { d8[p] = dh; b8[p] = bh; }
            f16x8 af[2];
#pragma unroll
            for (int ks = 0; ks < 2; ks++) {
                f16x8 h = d8 * cfA[ks] + b8 * cfB[ks] + cfC[ks];
                af[ks] = __builtin_elementwise_max(h, (f16x8)(_Float16)0.f);
            }
            f32x4 acc[4];
#pragma unroll
            for (int nt = 0; nt < 4; nt++) {
                acc[nt] = __builtin_amdgcn_mfma_f32_16x16x32_f16(af[0], wcf[0][nt], uacc[nt], 0, 0, 0);
                acc[nt] = __builtin_amdgcn_mfma_f32_16x16x32_f16(af[1], wcf[1][nt], acc[nt], 0, 0, 0);
            }
            float tr[4] = {0.f, 0.f, 0.f, 0.f};
#pragma unroll
            for (int nt = 0; nt < 4; nt++) {
#pragma unroll
                for (int r = 0; r < 4; r++) {
                    float s = acc[nt][r] + cu[ii][nt];
                    tr[r] = fmaf(fmaxf(s, 0.f), w2r[nt], tr[r]);
                }
            }
#pragma unroll
            for (int m = 1; m < 16; m <<= 1) {
#pragma unroll
                for (int r = 0; r < 4; r++) tr[r] += __shfl_xor(tr[r], m);
            }
            if (col == 0) {
#pragma unroll
                for (int r = 0; r < 4; r++)
                    ldsS[(jt * 16 + q * 4 + r) * 2 + ii] = tr[r];
            }
        }
    }
    __syncthreads();

    // ---- phase 2: row-local softmax + Sh, both rows fused ----
    float A = Wv1[lane], B = Wv1[64 + lane], C = bv1[lane];
    float2 sv = ((const float2*)ldsS)[t];
    float wm0 = sv.x, wm1 = sv.y;
#pragma unroll
    for (int md = 1; md < 64; md <<= 1) {
        wm0 = fmaxf(wm0, __shfl_xor(wm0, md));
        wm1 = fmaxf(wm1, __shfl_xor(wm1, md));
    }
    if (lane == 0) { ldsRedM[0][wv] = wm0; ldsRedM[1][wv] = wm1; }
    __syncthreads();
    float m0 = fmaxf(fmaxf(ldsRedM[0][0], ldsRedM[0][1]), fmaxf(ldsRedM[0][2], ldsRedM[0][3]));
    float m1 = fmaxf(fmaxf(ldsRedM[1][0], ldsRedM[1][1]), fmaxf(ldsRedM[1][2], ldsRedM[1][3]));
    float w0 = __expf(sv.x - m0), w1v = __expf(sv.y - m1);
    float rs0 = w0, rs1 = w1v;
#pragma unroll
    for (int md = 1; md < 64; md <<= 1) {
        rs0 += __shfl_xor(rs0, md);
        rs1 += __shfl_xor(rs1, md);
    }
    ((float2*)ldsS)[t] = make_float2(w0, w1v);
    if (lane == 0) { ldsRedS[0][wv] = rs0; ldsRedS[1][wv] = rs1; }
    __syncthreads();
    float rowsum0 = ldsRedS[0][0] + ldsRedS[0][1] + ldsRedS[0][2] + ldsRedS[0][3];
    float rowsum1 = ldsRedS[1][0] + ldsRedS[1][1] + ldsRedS[1][2] + ldsRedS[1][3];

    float acc0 = 0.f, acc1 = 0.f;      // lane = k; wave covers its 64 j's
#pragma unroll 8
    for (int jj = 0; jj < 64; jj++) {
        int j = wv * 64 + jj;
        float2 wj = ((const float2*)ldsS)[j];       // broadcast
        float4 db = ((const float4*)ldsDB)[j];      // broadcast
        float h0 = fmaxf(fmaf(db.x, A, fmaf(db.y, B, C)), 0.f);
        float h1 = fmaxf(fmaf(db.z, A, fmaf(db.w, B, C)), 0.f);
        acc0 = fmaf(wj.x, h0, acc0);
        acc1 = fmaf(wj.y, h1, acc1);
    }
    ldsP[0][wv][lane] = acc0;
    ldsP[1][wv][lane] = acc1;
    __syncthreads();
    if (t < 128) {
        int ii = t >> 6, k = t & 63;
        float sh = ldsP[ii][0][k] + ldsP[ii][1][k] + ldsP[ii][2][k] + ldsP[ii][3][k];
        ws[OFF_SHR + (b * 256 + i0 + ii) * 64 + k] = sh;
    }
    if (t == 0) {
        ws[OFF_MI  + b * 256 + i0]     = m0;
        ws[OFF_MI  + b * 256 + i0 + 1] = m1;
        ws[OFF_RSI + b * 256 + i0]     = rowsum0;
        ws[OFF_RSI + b * 256 + i0 + 1] = rowsum1;
    }
}

// ---------------------------------------------------------------- final ----
__global__ __launch_bounds__(256) void k_final(
    const float* __restrict__ values, const float* __restrict__ Wv2,
    const float* __restrict__ bv2, const float* __restrict__ ws,
    float* __restrict__ out)
{
    __shared__ float scl[256], zl[256], red[4], pS[4][64], pA[4][64], shv[64], a2v[64];
    int b = blockIdx.x, t = threadIdx.x, wv = t >> 6, lane = t & 63;

    float mi = ws[OFF_MI + b * 256 + t];
    float wm = mi;
#pragma unroll
    for (int md = 1; md < 64; md <<= 1) wm = fmaxf(wm, __shfl_xor(wm, md));
    if (lane == 0) red[wv] = wm;
    __syncthreads();
    float M = fmaxf(fmaxf(red[0], red[1]), fmaxf(red[2], red[3]));

    float rs = ws[OFF_RSI + b * 256 + t];
    float sc = __expf(mi - M);
    float zt = sc * rs;
    scl[t] = sc; zl[t] = zt;
    float zp = zt;
#pragma unroll
    for (int md = 1; md < 64; md <<= 1) zp += __shfl_xor(zp, md);
    __syncthreads();
    if (lane == 0) red[wv] = zp;
    __syncthreads();
    float Z = red[0] + red[1] + red[2] + red[3];

    float accS = 0.f, accA = 0.f;
    const float* shrB = ws + OFF_SHR + b * 256 * 64;
    const float* vB   = values + b * 256 * 64;
#pragma unroll 4
    for (int jj = 0; jj < 64; jj++) {
        int row = wv * 64 + jj;
        accS = fmaf(scl[row], shrB[row * 64 + lane], accS);
        accA = fmaf(zl[row],  vB[row * 64 + lane],  accA);
    }
    pS[wv][lane] = accS; pA[wv][lane] = accA;
    __syncthreads();
    if (t < 64) {
        shv[t] = pS[0][t] + pS[1][t] + pS[2][t] + pS[3][t];
        a2v[t] = pA[0][t] + pA[1][t] + pA[2][t] + pA[3][t];
    }
    __syncthreads();
    if (t < 64) {
        float t1 = 0.f;
#pragma unroll 8
        for (int k = 0; k < 64; k++) t1 = fmaf(shv[k], Wv2[k * 64 + t], t1);
        out[b * 64 + t] = 0.5f * (t1 + a2v[t]) / Z + 0.5f * bv2[t];
    }
}

// ---------------------------------------------------------------- launch ---
extern "C" void kernel_launch(void* const* d_in, const int* in_sizes, int n_in,
                              void* d_out, int out_size, void* d_ws, size_t ws_size,
                              hipStream_t stream)
{
    const float* positions = (const float*)d_in[0];
    const float* values    = (const float*)d_in[1];
    const float* Wv1       = (const float*)d_in[2];
    const float* bv1       = (const float*)d_in[3];
    const float* Wv2       = (const float*)d_in[4];
    const float* bv2       = (const float*)d_in[5];
    const float* Ws1       = (const float*)d_in[6];
    const float* bs1       = (const float*)d_in[7];
    const float* Ws2       = (const float*)d_in[8];
    // d_in[9] = bs2: uniform shift on scores, cancels in softmax
    float* ws  = (float*)d_ws;
    float* out = (float*)d_out;

    k_setup<<<45, 256, 0, stream>>>(Wv1, bv1, Wv2, bv2, Ws1, bs1, ws);
    k_main<<<1024, 256, 0, stream>>>(positions, values, Wv1, bv1, Ws2, ws);
    k_final<<<NB, 256, 0, stream>>>(values, Wv2, bv2, ws, out);
}